// Round 1
// 203.924 us; speedup vs baseline: 1.2035x; 1.2035x over previous
//
#include <hip/hip_runtime.h>
#include <stdint.h>

#define N_NODES 100000
#define FEAT 64
#define NB 64            // nodes per aggregation bucket (dstl in 6 bits)
#define SC_CHUNK 8192
#define NBKT 1563        // ceil(N_NODES / 64)
#define BKT_CAP 1400     // mean 1024, sigma 32 -> +11.7 sigma
#define BIAS 512.0f      // makes all layer-2 outputs positive: float bits monotone

typedef __attribute__((ext_vector_type(8))) _Float16 half8;  // 8 f16 (4 VGPRs)
typedef __attribute__((ext_vector_type(2))) _Float16 half2v;
typedef __attribute__((ext_vector_type(2))) __fp16 fp16x2;   // cvt_pkrtz result type
typedef __attribute__((ext_vector_type(4))) float f32x4;

// order-preserving float->u32 key (fallback path); 0 is an unreachable sentinel
__device__ __forceinline__ uint32_t enc_key(float f) {
    uint32_t u = __float_as_uint(f);
    return (u & 0x80000000u) ? ~u : (u | 0x80000000u);
}
__device__ __forceinline__ float dec_key(uint32_t k) {
    return __uint_as_float((k & 0x80000000u) ? (k & 0x7FFFFFFFu) : ~k);
}
__device__ __forceinline__ uint32_t pk_f16(float a, float b) {  // v_cvt_pkrtz
    union { fp16x2 h; uint32_t u; } cv;
    cv.h = __builtin_amdgcn_cvt_pkrtz(a, b);
    return cv.u;
}

// d_ws layout in 4-byte words:
// [0,4096)        W2T [64][64]         (fallback path only)
// [4096,8384)     AmB [67][64]         A - B  (A=W1[0:67], B=W1[67:134])
// [8384,12672)    Bm  [67][64]         B
// [12672,14720)   W2P f16[4096]        W2 pre-packed in B-fragment layout
// [16384,..)      U f16[N][64]; V f16[N][64]
// then gcnt u32[NBKT] (padded to 2048), sorted u32[NBKT * BKT_CAP]
#define W2T_OFF 0
#define AMB_OFF 4096
#define BM_OFF  8384
#define W2P_OFF 12672
#define U_OFF   16384
#define V_OFF   (U_OFF + N_NODES * FEAT / 2)
#define GCNT_OFF (U_OFF + N_NODES * FEAT)
#define SRT_OFF  (GCNT_OFF + 2048)

__global__ __launch_bounds__(256) void transform_kernel(
    const float* __restrict__ W1, const float* __restrict__ W2,
    float* __restrict__ ws, int full)
{
    int i = blockIdx.x * 256 + threadIdx.x;   // 16768 total
    if (full && i < 2048)                     // gcnt zero (replaces hipMemsetAsync)
        ((uint32_t*)ws)[GCNT_OFF + i] = 0u;
    if (i < 4096) {
        int c2 = i >> 6, c = i & 63;
        ws[W2T_OFF + i] = W2[c * 64 + c2];
    } else if (full && i < 8384) {
        int j = i - 4096;
        ws[AMB_OFF + j] = W1[j] - W1[j + 67 * 64];
    } else if (full && i < 12672) {
        int j = i - 8384;
        ws[BM_OFF + j] = W1[j + 67 * 64];
    } else if (full && i < 16768) {
        // B-fragment pack: idx = n4*1024 + h*512 + quad*128 + c2lo*8 + j
        int p = i - 12672;
        int j = p & 7, c2lo = (p >> 3) & 15, quad = (p >> 7) & 3;
        int h = (p >> 9) & 1, n4 = (p >> 10) & 3;
        int k = h * 32 + quad * 8 + j;
        int n = n4 * 16 + c2lo;
        ((_Float16*)(ws + W2P_OFF))[p] = (_Float16)W2[k * 64 + n];
    }
}

// ---------- per-node precompute, split by gridDim.y:
// half 0: U = f16(x @ (A-B) + b1)    half 1: V = f16(x @ B)
__global__ __launch_bounds__(256) void node_kernel(
    const float* __restrict__ xyz, const float* __restrict__ feat,
    const float* __restrict__ b1, const float* __restrict__ ws,
    uint16_t* __restrict__ U, uint16_t* __restrict__ V, int nN)
{
    int n = blockIdx.x * 256 + threadIdx.x;
    int half = blockIdx.y;                   // block-uniform -> scalar weight loads
    if (n >= nN) return;
    const float* __restrict__ W = ws + (half ? BM_OFF : AMB_OFF);

    float acc[FEAT];
    if (half == 0) {
        #pragma unroll
        for (int c = 0; c < FEAT; ++c) acc[c] = b1[c];
    } else {
        #pragma unroll
        for (int c = 0; c < FEAT; ++c) acc[c] = 0.0f;
    }

    const float* f = feat + (size_t)n * FEAT;
    #pragma unroll 1
    for (int k = 0; k < 64; k += 4) {
        float4 x4 = *(const float4*)(f + k);
        float xv[4] = {x4.x, x4.y, x4.z, x4.w};
        #pragma unroll
        for (int q = 0; q < 4; ++q) {
            const float* __restrict__ w = W + (k + q) * 64;
            #pragma unroll
            for (int c = 0; c < FEAT; ++c)
                acc[c] = fmaf(xv[q], w[c], acc[c]);
        }
    }
    const float* p = xyz + (size_t)n * 3;
    #pragma unroll
    for (int k3 = 0; k3 < 3; ++k3) {
        float xv = p[k3];
        const float* __restrict__ w = W + (64 + k3) * 64;
        #pragma unroll
        for (int c = 0; c < FEAT; ++c)
            acc[c] = fmaf(xv, w[c], acc[c]);
    }
    uint32_t* outp = (uint32_t*)((half ? V : U) + (size_t)n * FEAT);
    #pragma unroll
    for (int c = 0; c < 32; ++c)
        outp[c] = pk_f16(acc[2*c], acc[2*c+1]);
}

// ---------- single-pass coarse bucketing (64-node buckets, contiguous runs) ----
__global__ __launch_bounds__(256) void bucket_kernel(
    const int* __restrict__ ei, uint32_t* __restrict__ gcnt,
    uint32_t* __restrict__ sorted, int nE)
{
    __shared__ uint32_t svals[SC_CHUNK];   // 32 KB
    __shared__ uint16_t sbkt[SC_CHUNK];    // 16 KB
    __shared__ uint32_t hist[NBKT];        // counts -> cursor -> gbase
    __shared__ uint32_t base[NBKT + 1];
    __shared__ uint32_t segs[256];

    int t = threadIdx.x;
    int e0 = blockIdx.x * SC_CHUNK;
    int cnt = min(SC_CHUNK, nE - e0);

    for (int i = t; i < NBKT; i += 256) hist[i] = 0;
    __syncthreads();
    for (int i = t; i < cnt; i += 256) {
        int dst = ei[nE + e0 + i];
        atomicAdd(&hist[dst >> 6], 1u);
    }
    __syncthreads();
    // exclusive scan hist -> base (segmented: 256 threads x 7 entries)
    {
        const int SEG = 7;                 // 256*7 = 1792 >= NBKT
        int lo = t * SEG, hi = min(lo + SEG, NBKT);
        uint32_t s = 0;
        for (int i = lo; i < hi; ++i) s += hist[i];
        segs[t] = s;
        __syncthreads();
        for (int d = 1; d < 256; d <<= 1) {
            uint32_t x = (t >= d) ? segs[t - d] : 0;
            __syncthreads();
            segs[t] += x;
            __syncthreads();
        }
        uint32_t run = (t == 0) ? 0 : segs[t - 1];
        for (int i = lo; i < hi; ++i) { uint32_t c = hist[i]; base[i] = run; run += c; }
        if (t == 255) base[NBKT] = run;
    }
    __syncthreads();
    for (int i = t; i < NBKT; i += 256) hist[i] = base[i];   // cursor = base
    __syncthreads();
    // placement (re-read edges; they're L2-hot)
    for (int i = t; i < cnt; i += 256) {
        int src = ei[e0 + i];
        int dst = ei[nE + e0 + i];
        int b = dst >> 6;
        uint32_t pos = atomicAdd(&hist[b], 1u);
        svals[pos] = (uint32_t)src | ((uint32_t)(dst & 63) << 20);
        sbkt[pos] = (uint16_t)b;
    }
    __syncthreads();
    // reserve global space per bucket; hist <- global base
    for (int b = t; b < NBKT; b += 256) {
        uint32_t c = base[b + 1] - base[b];
        hist[b] = c ? atomicAdd(&gcnt[b], c) : 0u;
    }
    __syncthreads();
    // write contiguous runs
    for (int i = t; i < cnt; i += 256) {
        uint32_t b = sbkt[i];
        uint32_t off = hist[b] + ((uint32_t)i - base[b]);
        if (off < BKT_CAP)
            sorted[(size_t)b * BKT_CAP + off] = svals[i];
    }
}

// ---------- aggregation: LDS counting-sort + f16 MFMA (bias in acc) +
//            run-max + raw-bits LDS atomicMax (positive-float monotonicity)
// v2: depth-2 software pipeline on {ssrt, dst-run, V-row, U-row}; dsts via one
//     ds_read_b128 of the sorted run (ssrt padded +16) instead of 4 shfl;
//     branch-lean merge epilogue (4 predicated atomic blocks).
#define LOADE(G, DSV, VV0, VV1, UU0, UU1) do {                               \
        int e_c_ = min((G) + el, cnt - 1);                                   \
        uint32_t val_ = ssrt[e_c_];                                          \
        DSV = *(const uint4*)(ssrt + (G) + quad * 4);                        \
        int src_ = (int)(val_ & 0xFFFFFu);                                   \
        const uint32_t* vr_ = (const uint32_t*)(V + (size_t)src_ * FEAT);    \
        VV0 = *(const uint4*)(vr_ + quad * 4);                               \
        VV1 = *(const uint4*)(vr_ + 16 + quad * 4);                          \
        const uint32_t* ur_ = ushare + (int)(val_ >> 20) * 32;               \
        UU0 = *(const uint4*)(ur_ + quad * 4);                               \
        UU1 = *(const uint4*)(ur_ + 16 + quad * 4);                          \
    } while (0)

__global__ __launch_bounds__(256) void agg_kernel(
    const uint32_t* __restrict__ gcnt, const uint32_t* __restrict__ sorted,
    const uint16_t* __restrict__ U, const uint16_t* __restrict__ V,
    const float* __restrict__ ws_w2p, const float* __restrict__ b2,
    float* __restrict__ out, int nN)
{
    __shared__ int      lmax[NB * 65];       // 16.6 KB, biased-float bits, 0 = none
    __shared__ uint32_t ushare[NB * 32];     // 8 KB: 64 node rows x 64 f16
    __shared__ uint32_t ssrt[BKT_CAP + 16];  // 5.7 KB (+16 pad for uint4 run read)
    __shared__ uint32_t shist[NB];

    int bkt = blockIdx.x;
    int nb0 = bkt * NB;
    int rows = min(NB, nN - nb0);
    int cnt = min((int)gcnt[bkt], BKT_CAP);
    int t = threadIdx.x;

    for (int i = t; i < NB * 65; i += 256) lmax[i] = 0;
    if (t < NB) shist[t] = 0;
    {
        const uint32_t* usrc = (const uint32_t*)(U + (size_t)nb0 * FEAT);
        for (int i = t; i < rows * 32; i += 256) ushare[i] = usrc[i];
    }
    const uint32_t* bsrc = sorted + (size_t)bkt * BKT_CAP;
    __syncthreads();
    for (int i = t; i < cnt; i += 256)
        atomicAdd(&shist[bsrc[i] >> 20], 1u);
    __syncthreads();
    if (t < NB) {   // wave-0 exclusive scan of 64 counters
        uint32_t v = shist[t];
        uint32_t run = v;
        #pragma unroll
        for (int d = 1; d < 64; d <<= 1) {
            uint32_t x = (uint32_t)__shfl_up((int)run, (unsigned)d, 64);
            if (t >= d) run += x;
        }
        shist[t] = run - v;                // exclusive start = cursor
    }
    __syncthreads();
    for (int i = t; i < cnt; i += 256) {   // counting-sort placement (re-read)
        uint32_t v = bsrc[i];
        uint32_t pos = atomicAdd(&shist[v >> 20], 1u);
        ssrt[pos] = v;
    }
    __syncthreads();

    int lane = t & 63;
    int wave = t >> 6;
    int el = lane & 15, quad = lane >> 4;

    // B fragments (wave-uniform per lane): 8 frags of 16B
    const uint4* w2p = (const uint4*)ws_w2p;
    union { uint4 u4; half8 h8; } bfr[8];
    #pragma unroll
    for (int q8 = 0; q8 < 8; ++q8)              // q8 = n4*2 + h
        bfr[q8].u4 = w2p[(q8 * 4 + quad) * 16 + el];
    float b2v[4];
    #pragma unroll
    for (int n4 = 0; n4 < 4; ++n4) b2v[n4] = b2[n4 * 16 + el] + BIAS;

    const half2v zero2 = {(_Float16)0.0f, (_Float16)0.0f};

    // ---- pipelined main loop: iter g computes while iter g+64 loads ----
    uint4 dsv_c, vv_c0, vv_c1, uu_c0, uu_c1;
    int g = wave * 16;
    if (g < cnt) LOADE(g, dsv_c, vv_c0, vv_c1, uu_c0, uu_c1);

    #pragma unroll 1
    for (; g < cnt; g += 64) {
        int gn = g + 64;
        int gl = (gn < cnt) ? gn : g;       // last iter: redundant (valid) reload
        uint4 dsv_n, vv_n0, vv_n1, uu_n0, uu_n1;
        LOADE(gl, dsv_n, vv_n0, vv_n1, uu_n0, uu_n1);

        // build A fragments: relu(u+v) via packed f16 (2 ops per dword)
        union { uint4 u4; half8 h8; } afr[2];
        #pragma unroll
        for (int h = 0; h < 2; ++h) {
            uint4 uu = h ? uu_c1 : uu_c0;
            uint4 vv = h ? vv_c1 : vv_c0;
            uint32_t ua[4] = {uu.x, uu.y, uu.z, uu.w};
            uint32_t va[4] = {vv.x, vv.y, vv.z, vv.w};
            uint32_t pk[4];
            #pragma unroll
            for (int p = 0; p < 4; ++p) {
                union { uint32_t u; half2v h2; } cu, cv2, ct;
                cu.u = ua[p]; cv2.u = va[p];
                ct.h2 = __builtin_elementwise_max(cu.h2 + cv2.h2, zero2);
                pk[p] = ct.u;
            }
            afr[h].u4 = make_uint4(pk[0], pk[1], pk[2], pk[3]);
        }

        f32x4 acc[4];
        #pragma unroll
        for (int n4 = 0; n4 < 4; ++n4)      // bias+b2 pre-folded into accumulator
            acc[n4] = (f32x4){b2v[n4], b2v[n4], b2v[n4], b2v[n4]};
        #pragma unroll
        for (int n4 = 0; n4 < 4; ++n4) {
            acc[n4] = __builtin_amdgcn_mfma_f32_16x16x32_f16(afr[0].h8, bfr[n4*2+0].h8, acc[n4], 0, 0, 0);
            acc[n4] = __builtin_amdgcn_mfma_f32_16x16x32_f16(afr[1].h8, bfr[n4*2+1].h8, acc[n4], 0, 0, 0);
        }

        // dst_local for the 4 C-rows this lane holds (rows = quad*4+r), from the
        // sorted run itself; entries past cnt are pad-garbage but fully gated.
        int d0 = (int)(dsv_c.x >> 20), d1 = (int)(dsv_c.y >> 20);
        int d2 = (int)(dsv_c.z >> 20), d3 = (int)(dsv_c.w >> 20);
        int eb = g + quad * 4;
        bool ok0 = eb < cnt, ok1 = eb + 1 < cnt;
        bool ok2 = eb + 2 < cnt, ok3 = eb + 3 < cnt;
        bool m0 = (d0 == d1) & ok1;         // merge r into r+1 iff same dst & valid
        bool m1 = (d1 == d2) & ok2;
        bool m2 = (d2 == d3) & ok3;
        #pragma unroll
        for (int n4 = 0; n4 < 4; ++n4) {
            if (m0) acc[n4][1] = fmaxf(acc[n4][1], acc[n4][0]);
            if (m1) acc[n4][2] = fmaxf(acc[n4][2], acc[n4][1]);
            if (m2) acc[n4][3] = fmaxf(acc[n4][3], acc[n4][2]);
        }
        if (ok0 & !m0) {
            #pragma unroll
            for (int n4 = 0; n4 < 4; ++n4)
                atomicMax(&lmax[d0 * 65 + n4 * 16 + el], __float_as_int(acc[n4][0]));
        }
        if (ok1 & !m1) {
            #pragma unroll
            for (int n4 = 0; n4 < 4; ++n4)
                atomicMax(&lmax[d1 * 65 + n4 * 16 + el], __float_as_int(acc[n4][1]));
        }
        if (ok2 & !m2) {
            #pragma unroll
            for (int n4 = 0; n4 < 4; ++n4)
                atomicMax(&lmax[d2 * 65 + n4 * 16 + el], __float_as_int(acc[n4][2]));
        }
        if (ok3) {
            #pragma unroll
            for (int n4 = 0; n4 < 4; ++n4)
                atomicMax(&lmax[d3 * 65 + n4 * 16 + el], __float_as_int(acc[n4][3]));
        }

        dsv_c = dsv_n;
        vv_c0 = vv_n0; vv_c1 = vv_n1;
        uu_c0 = uu_n0; uu_c1 = uu_n1;
    }
    __syncthreads();

    for (int i = t; i < rows * FEAT; i += 256) {
        int r = i >> 6, c = i & 63;
        int k = lmax[r * 65 + c];
        out[(size_t)(nb0 + r) * FEAT + c] = k ? (__int_as_float(k) - BIAS) : 0.0f;
    }
}
#undef LOADE

// ---------- fallback (small ws): fused per-edge kernel (known-correct) ----------
__device__ __forceinline__ void rank1_update(
    float* __restrict__ h, float xi, float d,
    const float* __restrict__ A, const float* __restrict__ B)
{
    #pragma unroll
    for (int c = 0; c < FEAT; ++c)
        h[c] = fmaf(xi, A[c], fmaf(d, B[c], h[c]));
}

__global__ __launch_bounds__(256) void edge_fused_kernel(
    const float* __restrict__ xyz, const float* __restrict__ feat,
    const int* __restrict__ ei,
    const float* __restrict__ W1, const float* __restrict__ b1,
    const float* __restrict__ ws, const float* __restrict__ b2,
    uint32_t* __restrict__ keys, int nE)
{
    int e = blockIdx.x * 256 + threadIdx.x;
    if (e >= nE) return;
    int src = ei[e];
    int dst = ei[nE + e];
    const float* __restrict__ W2T = ws + W2T_OFF;

    float h[FEAT];
    #pragma unroll
    for (int c = 0; c < FEAT; ++c) h[c] = b1[c];

    const float* fi = feat + (size_t)dst * FEAT;
    const float* fj = feat + (size_t)src * FEAT;
    #pragma unroll 1
    for (int k = 0; k < 64; k += 4) {
        float4 a = *(const float4*)(fi + k);
        float4 b = *(const float4*)(fj + k);
        rank1_update(h, a.x, b.x - a.x, W1 + (k + 0) * 64, W1 + (67 + k + 0) * 64);
        rank1_update(h, a.y, b.y - a.y, W1 + (k + 1) * 64, W1 + (67 + k + 1) * 64);
        rank1_update(h, a.z, b.z - a.z, W1 + (k + 2) * 64, W1 + (67 + k + 2) * 64);
        rank1_update(h, a.w, b.w - a.w, W1 + (k + 3) * 64, W1 + (67 + k + 3) * 64);
    }
    {
        const float* pi = xyz + (size_t)dst * 3;
        const float* pj = xyz + (size_t)src * 3;
        #pragma unroll
        for (int k3 = 0; k3 < 3; ++k3) {
            float xi = pi[k3];
            rank1_update(h, xi, pj[k3] - xi, W1 + (64 + k3) * 64, W1 + (131 + k3) * 64);
        }
    }
    #pragma unroll
    for (int c = 0; c < FEAT; ++c) h[c] = fmaxf(h[c], 0.0f);

    uint32_t* krow = keys + (size_t)dst * FEAT;
    #pragma unroll 1
    for (int c2 = 0; c2 < FEAT; c2 += 4) {
        float o0 = b2[c2 + 0], o1 = b2[c2 + 1];
        float o2 = b2[c2 + 2], o3 = b2[c2 + 3];
        const float* w0 = W2T + (c2 + 0) * 64;
        const float* w1 = W2T + (c2 + 1) * 64;
        const float* w2 = W2T + (c2 + 2) * 64;
        const float* w3 = W2T + (c2 + 3) * 64;
        #pragma unroll
        for (int c = 0; c < FEAT; ++c) {
            float hv = h[c];
            o0 = fmaf(hv, w0[c], o0);
            o1 = fmaf(hv, w1[c], o1);
            o2 = fmaf(hv, w2[c], o2);
            o3 = fmaf(hv, w3[c], o3);
        }
        uint32_t k0 = enc_key(o0), k1 = enc_key(o1);
        uint32_t k2 = enc_key(o2), k3 = enc_key(o3);
        uint4 cur = *(const uint4*)(krow + c2);
        if (k0 > cur.x) atomicMax(&krow[c2 + 0], k0);
        if (k1 > cur.y) atomicMax(&krow[c2 + 1], k1);
        if (k2 > cur.z) atomicMax(&krow[c2 + 2], k2);
        if (k3 > cur.w) atomicMax(&krow[c2 + 3], k3);
    }
}

__global__ __launch_bounds__(256) void decode_kernel(
    uint32_t* __restrict__ keys, int n4)
{
    int i = blockIdx.x * 256 + threadIdx.x;
    if (i >= n4) return;
    uint4 k = ((const uint4*)keys)[i];
    float4 r;
    r.x = k.x ? dec_key(k.x) : 0.0f;
    r.y = k.y ? dec_key(k.y) : 0.0f;
    r.z = k.z ? dec_key(k.z) : 0.0f;
    r.w = k.w ? dec_key(k.w) : 0.0f;
    ((float4*)keys)[i] = r;
}

extern "C" void kernel_launch(void* const* d_in, const int* in_sizes, int n_in,
                              void* d_out, int out_size, void* d_ws, size_t ws_size,
                              hipStream_t stream)
{
    const float* xyz  = (const float*)d_in[0];
    const float* feat = (const float*)d_in[1];
    const int*   ei   = (const int*)d_in[2];
    const float* W1   = (const float*)d_in[3];
    const float* b1   = (const float*)d_in[4];
    const float* W2   = (const float*)d_in[5];
    const float* b2   = (const float*)d_in[6];

    int nE = in_sizes[2] / 2;
    float* ws = (float*)d_ws;

    size_t need_words = (size_t)SRT_OFF + (size_t)NBKT * BKT_CAP;
    int full = (ws_size >= need_words * 4) ? 1 : 0;

    transform_kernel<<<66, 256, 0, stream>>>(W1, W2, ws, full);

    if (full) {
        uint16_t* U = (uint16_t*)(ws + U_OFF);
        uint16_t* V = (uint16_t*)(ws + V_OFF);
        uint32_t* gcnt   = (uint32_t*)(ws + GCNT_OFF);
        uint32_t* sorted = (uint32_t*)(ws + SRT_OFF);

        dim3 ngrid((N_NODES + 255) / 256, 2);
        node_kernel<<<ngrid, 256, 0, stream>>>(xyz, feat, b1, ws, U, V, N_NODES);
        bucket_kernel<<<(nE + SC_CHUNK - 1) / SC_CHUNK, 256, 0, stream>>>(
            ei, gcnt, sorted, nE);
        agg_kernel<<<NBKT, 256, 0, stream>>>(
            gcnt, sorted, U, V, ws + W2P_OFF, b2, (float*)d_out, N_NODES);
    } else {
        uint32_t* keys = (uint32_t*)d_out;
        hipMemsetAsync(d_out, 0, (size_t)out_size * sizeof(float), stream);
        edge_fused_kernel<<<(nE + 255) / 256, 256, 0, stream>>>(
            xyz, feat, ei, W1, b1, ws, b2, keys, nE);
        decode_kernel<<<(out_size / 4 + 255) / 256, 256, 0, stream>>>(
            keys, out_size / 4);
    }
}

// Round 2
// 175.015 us; speedup vs baseline: 1.4023x; 1.1652x over previous
//
#include <hip/hip_runtime.h>
#include <stdint.h>

#define N_NODES 100000
#define FEAT 64
#define NB 64            // nodes per aggregation bucket (dstl in 6 bits)
#define SC_CHUNK 8192
#define NBKT 1563        // ceil(N_NODES / 64)
#define BKT_CAP 1400     // mean 1024, sigma 32 -> +11.7 sigma
#define RVN 6            // ceil(BKT_CAP / 256) register-held sorted entries
#define BIAS 512.0f      // makes all layer-2 outputs positive: float bits monotone

typedef __attribute__((ext_vector_type(8))) _Float16 half8;  // 8 f16 (4 VGPRs)
typedef __attribute__((ext_vector_type(2))) _Float16 half2v;
typedef __attribute__((ext_vector_type(2))) __fp16 fp16x2;   // cvt_pkrtz result type
typedef __attribute__((ext_vector_type(4))) float f32x4;

// order-preserving float->u32 key (fallback path); 0 is an unreachable sentinel
__device__ __forceinline__ uint32_t enc_key(float f) {
    uint32_t u = __float_as_uint(f);
    return (u & 0x80000000u) ? ~u : (u | 0x80000000u);
}
__device__ __forceinline__ float dec_key(uint32_t k) {
    return __uint_as_float((k & 0x80000000u) ? (k & 0x7FFFFFFFu) : ~k);
}
__device__ __forceinline__ uint32_t pk_f16(float a, float b) {  // v_cvt_pkrtz
    union { fp16x2 h; uint32_t u; } cv;
    cv.h = __builtin_amdgcn_cvt_pkrtz(a, b);
    return cv.u;
}

// d_ws layout in 4-byte words:
// [0,4096)        W2T [64][64]         (fallback path only)
// [4096,8384)     AmB [67][64]         A - B  (A=W1[0:67], B=W1[67:134])
// [8384,12672)    Bm  [67][64]         B
// [12672,14720)   W2P f16[4096]        W2 pre-packed in B-fragment layout
// [16384,..)      U f16[N][64]; V f16[N][64]
// then gcnt u32[NBKT] (padded to 2048), sorted u32[NBKT * BKT_CAP]
#define W2T_OFF 0
#define AMB_OFF 4096
#define BM_OFF  8384
#define W2P_OFF 12672
#define U_OFF   16384
#define V_OFF   (U_OFF + N_NODES * FEAT / 2)
#define GCNT_OFF (U_OFF + N_NODES * FEAT)
#define SRT_OFF  (GCNT_OFF + 2048)

__global__ __launch_bounds__(256) void transform_kernel(
    const float* __restrict__ W1, const float* __restrict__ W2,
    float* __restrict__ ws, int full)
{
    int i = blockIdx.x * 256 + threadIdx.x;   // 16768 total
    if (full && i < 2048)                     // gcnt zero (replaces hipMemsetAsync)
        ((uint32_t*)ws)[GCNT_OFF + i] = 0u;
    if (i < 4096) {
        int c2 = i >> 6, c = i & 63;
        ws[W2T_OFF + i] = W2[c * 64 + c2];
    } else if (full && i < 8384) {
        int j = i - 4096;
        ws[AMB_OFF + j] = W1[j] - W1[j + 67 * 64];
    } else if (full && i < 12672) {
        int j = i - 8384;
        ws[BM_OFF + j] = W1[j + 67 * 64];
    } else if (full && i < 16768) {
        // B-fragment pack: idx = n4*1024 + h*512 + quad*128 + c2lo*8 + j
        int p = i - 12672;
        int j = p & 7, c2lo = (p >> 3) & 15, quad = (p >> 7) & 3;
        int h = (p >> 9) & 1, n4 = (p >> 10) & 3;
        int k = h * 32 + quad * 8 + j;
        int n = n4 * 16 + c2lo;
        ((_Float16*)(ws + W2P_OFF))[p] = (_Float16)W2[k * 64 + n];
    }
}

// ---------- FUSED node precompute + edge bucketing --------------------------
// Bucket blocks come FIRST (blockIdx.x < nBkt) so their latency-bound phases
// start immediately; node blocks (VALU-bound) fill the remaining CUs and hide
// the bucket blocks' global-load/atomic latency.
// node half 0: U = f16(x @ (A-B) + b1)    half 1: V = f16(x @ B)
__global__ __launch_bounds__(256) void nodebkt_kernel(
    const float* __restrict__ xyz, const float* __restrict__ feat,
    const float* __restrict__ b1, const float* __restrict__ ws,
    uint16_t* __restrict__ U, uint16_t* __restrict__ V, int nN,
    const int* __restrict__ ei, uint32_t* __restrict__ gcnt,
    uint32_t* __restrict__ sorted, int nE, int nBkt)
{
    __shared__ uint32_t svals[SC_CHUNK];   // 32 KB
    __shared__ uint16_t sbkt[SC_CHUNK];    // 16 KB
    __shared__ uint32_t hist[NBKT];        // counts -> cursor -> gbase
    __shared__ uint32_t base[NBKT + 1];
    __shared__ uint32_t segs[256];

    int t = threadIdx.x;

    if ((int)blockIdx.x < nBkt) {
        // ---------------- bucket path ----------------
        int e0 = blockIdx.x * SC_CHUNK;
        int cnt = min(SC_CHUNK, nE - e0);
        int cnt4 = cnt & ~3;

        for (int i = t; i < NBKT; i += 256) hist[i] = 0;
        __syncthreads();
        // histogram (x4 vectorized loads)
        for (int i = t * 4; i < cnt4; i += 1024) {
            uint4 d4 = *(const uint4*)(ei + nE + e0 + i);
            atomicAdd(&hist[d4.x >> 6], 1u);
            atomicAdd(&hist[d4.y >> 6], 1u);
            atomicAdd(&hist[d4.z >> 6], 1u);
            atomicAdd(&hist[d4.w >> 6], 1u);
        }
        for (int i = cnt4 + t; i < cnt; i += 256)
            atomicAdd(&hist[ei[nE + e0 + i] >> 6], 1u);
        __syncthreads();
        // exclusive scan hist -> base (segmented: 256 threads x 7 entries)
        {
            const int SEG = 7;                 // 256*7 = 1792 >= NBKT
            int lo = t * SEG, hi = min(lo + SEG, NBKT);
            uint32_t s = 0;
            for (int i = lo; i < hi; ++i) s += hist[i];
            segs[t] = s;
            __syncthreads();
            for (int d = 1; d < 256; d <<= 1) {
                uint32_t x = (t >= d) ? segs[t - d] : 0;
                __syncthreads();
                segs[t] += x;
                __syncthreads();
            }
            uint32_t run = (t == 0) ? 0 : segs[t - 1];
            for (int i = lo; i < hi; ++i) { uint32_t c = hist[i]; base[i] = run; run += c; }
            if (t == 255) base[NBKT] = run;
        }
        __syncthreads();
        for (int i = t; i < NBKT; i += 256) hist[i] = base[i];   // cursor = base
        __syncthreads();
        // placement (x4 vectorized loads; edges L2-hot from histogram pass)
        for (int i = t * 4; i < cnt4; i += 1024) {
            uint4 s4 = *(const uint4*)(ei + e0 + i);
            uint4 d4 = *(const uint4*)(ei + nE + e0 + i);
            uint32_t sa[4] = {(uint32_t)s4.x, (uint32_t)s4.y, (uint32_t)s4.z, (uint32_t)s4.w};
            uint32_t da[4] = {(uint32_t)d4.x, (uint32_t)d4.y, (uint32_t)d4.z, (uint32_t)d4.w};
            #pragma unroll
            for (int k = 0; k < 4; ++k) {
                uint32_t b = da[k] >> 6;
                uint32_t pos = atomicAdd(&hist[b], 1u);
                svals[pos] = sa[k] | ((da[k] & 63u) << 20);
                sbkt[pos] = (uint16_t)b;
            }
        }
        for (int i = cnt4 + t; i < cnt; i += 256) {
            uint32_t src = (uint32_t)ei[e0 + i];
            uint32_t dst = (uint32_t)ei[nE + e0 + i];
            uint32_t b = dst >> 6;
            uint32_t pos = atomicAdd(&hist[b], 1u);
            svals[pos] = src | ((dst & 63u) << 20);
            sbkt[pos] = (uint16_t)b;
        }
        __syncthreads();
        // reserve global space per bucket; hist <- global base
        for (int b = t; b < NBKT; b += 256) {
            uint32_t c = base[b + 1] - base[b];
            hist[b] = c ? atomicAdd(&gcnt[b], c) : 0u;
        }
        __syncthreads();
        // write contiguous runs (x4 vectorized LDS reads)
        for (int i = t * 4; i < cnt4; i += 1024) {
            ushort4 b4 = *(const ushort4*)(sbkt + i);
            uint4 v4 = *(const uint4*)(svals + i);
            uint32_t ba[4] = {b4.x, b4.y, b4.z, b4.w};
            uint32_t va[4] = {v4.x, v4.y, v4.z, v4.w};
            #pragma unroll
            for (int k = 0; k < 4; ++k) {
                uint32_t b = ba[k];
                uint32_t off = hist[b] + ((uint32_t)(i + k) - base[b]);
                if (off < BKT_CAP)
                    sorted[(size_t)b * BKT_CAP + off] = va[k];
            }
        }
        for (int i = cnt4 + t; i < cnt; i += 256) {
            uint32_t b = sbkt[i];
            uint32_t off = hist[b] + ((uint32_t)i - base[b]);
            if (off < BKT_CAP)
                sorted[(size_t)b * BKT_CAP + off] = svals[i];
        }
        return;
    }

    // ---------------- node path ----------------
    int nb = blockIdx.x - nBkt;
    int half = nb & 1;                       // block-uniform -> scalar weight loads
    int n = (nb >> 1) * 256 + t;
    if (n >= nN) return;
    const float* __restrict__ W = ws + (half ? BM_OFF : AMB_OFF);

    float acc[FEAT];
    if (half == 0) {
        #pragma unroll
        for (int c = 0; c < FEAT; ++c) acc[c] = b1[c];
    } else {
        #pragma unroll
        for (int c = 0; c < FEAT; ++c) acc[c] = 0.0f;
    }

    const float* f = feat + (size_t)n * FEAT;
    #pragma unroll 1
    for (int k = 0; k < 64; k += 4) {
        float4 x4 = *(const float4*)(f + k);
        float xv[4] = {x4.x, x4.y, x4.z, x4.w};
        #pragma unroll
        for (int q = 0; q < 4; ++q) {
            const float* __restrict__ w = W + (k + q) * 64;
            #pragma unroll
            for (int c = 0; c < FEAT; ++c)
                acc[c] = fmaf(xv[q], w[c], acc[c]);
        }
    }
    const float* p = xyz + (size_t)n * 3;
    #pragma unroll
    for (int k3 = 0; k3 < 3; ++k3) {
        float xv = p[k3];
        const float* __restrict__ w = W + (64 + k3) * 64;
        #pragma unroll
        for (int c = 0; c < FEAT; ++c)
            acc[c] = fmaf(xv, w[c], acc[c]);
    }
    uint4* outp = (uint4*)((half ? V : U) + (size_t)n * FEAT);
    #pragma unroll
    for (int q = 0; q < 8; ++q) {
        uint4 o;
        o.x = pk_f16(acc[8*q + 0], acc[8*q + 1]);
        o.y = pk_f16(acc[8*q + 2], acc[8*q + 3]);
        o.z = pk_f16(acc[8*q + 4], acc[8*q + 5]);
        o.w = pk_f16(acc[8*q + 6], acc[8*q + 7]);
        outp[q] = o;
    }
}

// ---------- aggregation: LDS counting-sort + f16 MFMA (bias in acc) +
//            run-max + raw-bits LDS atomicMax (positive-float monotonicity)
// v2: depth-2 software pipeline; dsts via ds_read_b128 of the sorted run.
// v3: register-held sorted entries (single global read of bucket segment);
//     vectorized ushare copy and output epilogue.
#define LOADE(G, DSV, VV0, VV1, UU0, UU1) do {                               \
        int e_c_ = min((G) + el, cnt - 1);                                   \
        uint32_t val_ = ssrt[e_c_];                                          \
        DSV = *(const uint4*)(ssrt + (G) + quad * 4);                        \
        int src_ = (int)(val_ & 0xFFFFFu);                                   \
        const uint32_t* vr_ = (const uint32_t*)(V + (size_t)src_ * FEAT);    \
        VV0 = *(const uint4*)(vr_ + quad * 4);                               \
        VV1 = *(const uint4*)(vr_ + 16 + quad * 4);                          \
        const uint32_t* ur_ = ushare + (int)(val_ >> 20) * 32;               \
        UU0 = *(const uint4*)(ur_ + quad * 4);                               \
        UU1 = *(const uint4*)(ur_ + 16 + quad * 4);                          \
    } while (0)

__global__ __launch_bounds__(256) void agg_kernel(
    const uint32_t* __restrict__ gcnt, const uint32_t* __restrict__ sorted,
    const uint16_t* __restrict__ U, const uint16_t* __restrict__ V,
    const float* __restrict__ ws_w2p, const float* __restrict__ b2,
    float* __restrict__ out, int nN)
{
    __shared__ int      lmax[NB * 65];       // 16.6 KB, biased-float bits, 0 = none
    __shared__ uint32_t ushare[NB * 32];     // 8 KB: 64 node rows x 64 f16
    __shared__ uint32_t ssrt[BKT_CAP + 16];  // 5.7 KB (+16 pad for uint4 run read)
    __shared__ uint32_t shist[NB];

    int bkt = blockIdx.x;
    int nb0 = bkt * NB;
    int rows = min(NB, nN - nb0);
    int cnt = min((int)gcnt[bkt], BKT_CAP);
    int t = threadIdx.x;

    for (int i = t; i < NB * 65; i += 256) lmax[i] = 0;
    if (t < NB) shist[t] = 0;
    {
        const uint4* usrc4 = (const uint4*)(U + (size_t)nb0 * FEAT);
        for (int i = t; i < rows * 8; i += 256) ((uint4*)ushare)[i] = usrc4[i];
    }
    const uint32_t* bsrc = sorted + (size_t)bkt * BKT_CAP;
    __syncthreads();

    // single global read of the bucket segment, held in registers
    uint32_t rv[RVN];
    #pragma unroll
    for (int j = 0; j < RVN; ++j) {
        int i = t + j * 256;
        if (i < cnt) {
            uint32_t v = bsrc[i];
            rv[j] = v;
            atomicAdd(&shist[v >> 20], 1u);
        }
    }
    __syncthreads();
    if (t < NB) {   // wave-0 exclusive scan of 64 counters
        uint32_t v = shist[t];
        uint32_t run = v;
        #pragma unroll
        for (int d = 1; d < 64; d <<= 1) {
            uint32_t x = (uint32_t)__shfl_up((int)run, (unsigned)d, 64);
            if (t >= d) run += x;
        }
        shist[t] = run - v;                // exclusive start = cursor
    }
    __syncthreads();
    #pragma unroll
    for (int j = 0; j < RVN; ++j) {        // counting-sort placement from regs
        int i = t + j * 256;
        if (i < cnt) {
            uint32_t v = rv[j];
            uint32_t pos = atomicAdd(&shist[v >> 20], 1u);
            ssrt[pos] = v;
        }
    }
    __syncthreads();

    int lane = t & 63;
    int wave = t >> 6;
    int el = lane & 15, quad = lane >> 4;

    // B fragments (wave-uniform per lane): 8 frags of 16B
    const uint4* w2p = (const uint4*)ws_w2p;
    union { uint4 u4; half8 h8; } bfr[8];
    #pragma unroll
    for (int q8 = 0; q8 < 8; ++q8)              // q8 = n4*2 + h
        bfr[q8].u4 = w2p[(q8 * 4 + quad) * 16 + el];
    float b2v[4];
    #pragma unroll
    for (int n4 = 0; n4 < 4; ++n4) b2v[n4] = b2[n4 * 16 + el] + BIAS;

    const half2v zero2 = {(_Float16)0.0f, (_Float16)0.0f};

    // ---- pipelined main loop: iter g computes while iter g+64 loads ----
    uint4 dsv_c, vv_c0, vv_c1, uu_c0, uu_c1;
    int g = wave * 16;
    if (g < cnt) LOADE(g, dsv_c, vv_c0, vv_c1, uu_c0, uu_c1);

    #pragma unroll 1
    for (; g < cnt; g += 64) {
        int gn = g + 64;
        int gl = (gn < cnt) ? gn : g;       // last iter: redundant (valid) reload
        uint4 dsv_n, vv_n0, vv_n1, uu_n0, uu_n1;
        LOADE(gl, dsv_n, vv_n0, vv_n1, uu_n0, uu_n1);

        // build A fragments: relu(u+v) via packed f16 (2 ops per dword)
        union { uint4 u4; half8 h8; } afr[2];
        #pragma unroll
        for (int h = 0; h < 2; ++h) {
            uint4 uu = h ? uu_c1 : uu_c0;
            uint4 vv = h ? vv_c1 : vv_c0;
            uint32_t ua[4] = {uu.x, uu.y, uu.z, uu.w};
            uint32_t va[4] = {vv.x, vv.y, vv.z, vv.w};
            uint32_t pk[4];
            #pragma unroll
            for (int p = 0; p < 4; ++p) {
                union { uint32_t u; half2v h2; } cu, cv2, ct;
                cu.u = ua[p]; cv2.u = va[p];
                ct.h2 = __builtin_elementwise_max(cu.h2 + cv2.h2, zero2);
                pk[p] = ct.u;
            }
            afr[h].u4 = make_uint4(pk[0], pk[1], pk[2], pk[3]);
        }

        f32x4 acc[4];
        #pragma unroll
        for (int n4 = 0; n4 < 4; ++n4)      // bias+b2 pre-folded into accumulator
            acc[n4] = (f32x4){b2v[n4], b2v[n4], b2v[n4], b2v[n4]};
        #pragma unroll
        for (int n4 = 0; n4 < 4; ++n4) {
            acc[n4] = __builtin_amdgcn_mfma_f32_16x16x32_f16(afr[0].h8, bfr[n4*2+0].h8, acc[n4], 0, 0, 0);
            acc[n4] = __builtin_amdgcn_mfma_f32_16x16x32_f16(afr[1].h8, bfr[n4*2+1].h8, acc[n4], 0, 0, 0);
        }

        // dst_local for the 4 C-rows this lane holds (rows = quad*4+r), from the
        // sorted run itself; entries past cnt are pad-garbage but fully gated.
        int d0 = (int)(dsv_c.x >> 20), d1 = (int)(dsv_c.y >> 20);
        int d2 = (int)(dsv_c.z >> 20), d3 = (int)(dsv_c.w >> 20);
        int eb = g + quad * 4;
        bool ok0 = eb < cnt, ok1 = eb + 1 < cnt;
        bool ok2 = eb + 2 < cnt, ok3 = eb + 3 < cnt;
        bool m0 = (d0 == d1) & ok1;         // merge r into r+1 iff same dst & valid
        bool m1 = (d1 == d2) & ok2;
        bool m2 = (d2 == d3) & ok3;
        #pragma unroll
        for (int n4 = 0; n4 < 4; ++n4) {
            if (m0) acc[n4][1] = fmaxf(acc[n4][1], acc[n4][0]);
            if (m1) acc[n4][2] = fmaxf(acc[n4][2], acc[n4][1]);
            if (m2) acc[n4][3] = fmaxf(acc[n4][3], acc[n4][2]);
        }
        if (ok0 & !m0) {
            #pragma unroll
            for (int n4 = 0; n4 < 4; ++n4)
                atomicMax(&lmax[d0 * 65 + n4 * 16 + el], __float_as_int(acc[n4][0]));
        }
        if (ok1 & !m1) {
            #pragma unroll
            for (int n4 = 0; n4 < 4; ++n4)
                atomicMax(&lmax[d1 * 65 + n4 * 16 + el], __float_as_int(acc[n4][1]));
        }
        if (ok2 & !m2) {
            #pragma unroll
            for (int n4 = 0; n4 < 4; ++n4)
                atomicMax(&lmax[d2 * 65 + n4 * 16 + el], __float_as_int(acc[n4][2]));
        }
        if (ok3) {
            #pragma unroll
            for (int n4 = 0; n4 < 4; ++n4)
                atomicMax(&lmax[d3 * 65 + n4 * 16 + el], __float_as_int(acc[n4][3]));
        }

        dsv_c = dsv_n;
        vv_c0 = vv_n0; vv_c1 = vv_n1;
        uu_c0 = uu_n0; uu_c1 = uu_n1;
    }
    __syncthreads();

    for (int i = t * 4; i < rows * FEAT; i += 1024) {
        int r = i >> 6, c = i & 63;
        int lb = r * 65 + c;
        int k0 = lmax[lb + 0], k1 = lmax[lb + 1];
        int k2 = lmax[lb + 2], k3 = lmax[lb + 3];
        float4 o;
        o.x = k0 ? (__int_as_float(k0) - BIAS) : 0.0f;
        o.y = k1 ? (__int_as_float(k1) - BIAS) : 0.0f;
        o.z = k2 ? (__int_as_float(k2) - BIAS) : 0.0f;
        o.w = k3 ? (__int_as_float(k3) - BIAS) : 0.0f;
        *(float4*)(out + (size_t)(nb0 + r) * FEAT + c) = o;
    }
}
#undef LOADE

// ---------- fallback (small ws): fused per-edge kernel (known-correct) ----------
__device__ __forceinline__ void rank1_update(
    float* __restrict__ h, float xi, float d,
    const float* __restrict__ A, const float* __restrict__ B)
{
    #pragma unroll
    for (int c = 0; c < FEAT; ++c)
        h[c] = fmaf(xi, A[c], fmaf(d, B[c], h[c]));
}

__global__ __launch_bounds__(256) void edge_fused_kernel(
    const float* __restrict__ xyz, const float* __restrict__ feat,
    const int* __restrict__ ei,
    const float* __restrict__ W1, const float* __restrict__ b1,
    const float* __restrict__ ws, const float* __restrict__ b2,
    uint32_t* __restrict__ keys, int nE)
{
    int e = blockIdx.x * 256 + threadIdx.x;
    if (e >= nE) return;
    int src = ei[e];
    int dst = ei[nE + e];
    const float* __restrict__ W2T = ws + W2T_OFF;

    float h[FEAT];
    #pragma unroll
    for (int c = 0; c < FEAT; ++c) h[c] = b1[c];

    const float* fi = feat + (size_t)dst * FEAT;
    const float* fj = feat + (size_t)src * FEAT;
    #pragma unroll 1
    for (int k = 0; k < 64; k += 4) {
        float4 a = *(const float4*)(fi + k);
        float4 b = *(const float4*)(fj + k);
        rank1_update(h, a.x, b.x - a.x, W1 + (k + 0) * 64, W1 + (67 + k + 0) * 64);
        rank1_update(h, a.y, b.y - a.y, W1 + (k + 1) * 64, W1 + (67 + k + 1) * 64);
        rank1_update(h, a.z, b.z - a.z, W1 + (k + 2) * 64, W1 + (67 + k + 2) * 64);
        rank1_update(h, a.w, b.w - a.w, W1 + (k + 3) * 64, W1 + (67 + k + 3) * 64);
    }
    {
        const float* pi = xyz + (size_t)dst * 3;
        const float* pj = xyz + (size_t)src * 3;
        #pragma unroll
        for (int k3 = 0; k3 < 3; ++k3) {
            float xi = pi[k3];
            rank1_update(h, xi, pj[k3] - xi, W1 + (64 + k3) * 64, W1 + (131 + k3) * 64);
        }
    }
    #pragma unroll
    for (int c = 0; c < FEAT; ++c) h[c] = fmaxf(h[c], 0.0f);

    uint32_t* krow = keys + (size_t)dst * FEAT;
    #pragma unroll 1
    for (int c2 = 0; c2 < FEAT; c2 += 4) {
        float o0 = b2[c2 + 0], o1 = b2[c2 + 1];
        float o2 = b2[c2 + 2], o3 = b2[c2 + 3];
        const float* w0 = W2T + (c2 + 0) * 64;
        const float* w1 = W2T + (c2 + 1) * 64;
        const float* w2 = W2T + (c2 + 2) * 64;
        const float* w3 = W2T + (c2 + 3) * 64;
        #pragma unroll
        for (int c = 0; c < FEAT; ++c) {
            float hv = h[c];
            o0 = fmaf(hv, w0[c], o0);
            o1 = fmaf(hv, w1[c], o1);
            o2 = fmaf(hv, w2[c], o2);
            o3 = fmaf(hv, w3[c], o3);
        }
        uint32_t k0 = enc_key(o0), k1 = enc_key(o1);
        uint32_t k2 = enc_key(o2), k3 = enc_key(o3);
        uint4 cur = *(const uint4*)(krow + c2);
        if (k0 > cur.x) atomicMax(&krow[c2 + 0], k0);
        if (k1 > cur.y) atomicMax(&krow[c2 + 1], k1);
        if (k2 > cur.z) atomicMax(&krow[c2 + 2], k2);
        if (k3 > cur.w) atomicMax(&krow[c2 + 3], k3);
    }
}

__global__ __launch_bounds__(256) void decode_kernel(
    uint32_t* __restrict__ keys, int n4)
{
    int i = blockIdx.x * 256 + threadIdx.x;
    if (i >= n4) return;
    uint4 k = ((const uint4*)keys)[i];
    float4 r;
    r.x = k.x ? dec_key(k.x) : 0.0f;
    r.y = k.y ? dec_key(k.y) : 0.0f;
    r.z = k.z ? dec_key(k.z) : 0.0f;
    r.w = k.w ? dec_key(k.w) : 0.0f;
    ((float4*)keys)[i] = r;
}

extern "C" void kernel_launch(void* const* d_in, const int* in_sizes, int n_in,
                              void* d_out, int out_size, void* d_ws, size_t ws_size,
                              hipStream_t stream)
{
    const float* xyz  = (const float*)d_in[0];
    const float* feat = (const float*)d_in[1];
    const int*   ei   = (const int*)d_in[2];
    const float* W1   = (const float*)d_in[3];
    const float* b1   = (const float*)d_in[4];
    const float* W2   = (const float*)d_in[5];
    const float* b2   = (const float*)d_in[6];

    int nE = in_sizes[2] / 2;
    float* ws = (float*)d_ws;

    size_t need_words = (size_t)SRT_OFF + (size_t)NBKT * BKT_CAP;
    int full = (ws_size >= need_words * 4) ? 1 : 0;

    transform_kernel<<<66, 256, 0, stream>>>(W1, W2, ws, full);

    if (full) {
        uint16_t* U = (uint16_t*)(ws + U_OFF);
        uint16_t* V = (uint16_t*)(ws + V_OFF);
        uint32_t* gcnt   = (uint32_t*)(ws + GCNT_OFF);
        uint32_t* sorted = (uint32_t*)(ws + SRT_OFF);

        int nBkt = (nE + SC_CHUNK - 1) / SC_CHUNK;
        int nodeBlocks = ((N_NODES + 255) / 256) * 2;
        nodebkt_kernel<<<nBkt + nodeBlocks, 256, 0, stream>>>(
            xyz, feat, b1, ws, U, V, N_NODES, ei, gcnt, sorted, nE, nBkt);
        agg_kernel<<<NBKT, 256, 0, stream>>>(
            gcnt, sorted, U, V, ws + W2P_OFF, b2, (float*)d_out, N_NODES);
    } else {
        uint32_t* keys = (uint32_t*)d_out;
        hipMemsetAsync(d_out, 0, (size_t)out_size * sizeof(float), stream);
        edge_fused_kernel<<<(nE + 255) / 256, 256, 0, stream>>>(
            xyz, feat, ei, W1, b1, ws, b2, keys, nE);
        decode_kernel<<<(out_size / 4 + 255) / 256, 256, 0, stream>>>(
            keys, out_size / 4);
    }
}